// Round 3
// baseline (177.815 us; speedup 1.0000x reference)
//
#include <hip/hip_runtime.h>

#define DDIM 128
#define RDIM 32
#define BLK  256

typedef __attribute__((ext_vector_type(8))) short bf16x8;
typedef __attribute__((ext_vector_type(4))) float f32x4;

__device__ __forceinline__ float tanh_fast(float v) {
  float e = __expf(2.f * v);           // v>>0 -> inf -> 1; v<<0 -> 0 -> -1
  return 1.f - 2.f / (e + 1.f);
}
__device__ __forceinline__ float sigmoid_fast(float v) {
  return 1.f / (1.f + __expf(-v));
}
__device__ __forceinline__ unsigned short f2bf(float f) {  // RNE f32->bf16
  unsigned u = __float_as_uint(f);
  u += 0x7fffu + ((u >> 16) & 1u);
  return (unsigned short)(u >> 16);
}
__device__ __forceinline__ float bf2f(unsigned short s) {
  return __uint_as_float(((unsigned)s) << 16);
}
__device__ __forceinline__ int lower_bound(const int* __restrict__ b, int n, int v) {
  int lo = 0, hi = n;
  while (lo < hi) { int m = (lo + hi) >> 1; if (b[m] < v) lo = m + 1; else hi = m; }
  return lo;
}

// ---------------------------------------------------------------------------
// K0: one-time build of bf16 MFMA weight fragments in ws.
//   w1f: [frag=nt*4+kk][lane][8]  (2 nt x 4 kk x 64 lanes x 8) = 4096 bf16
//   w2f: [nt][lane][8]            (8 nt x 64 lanes x 8)        = 4096 bf16
// B-frag layout (16x16x32): col=l&15, k=(l>>4)*8+j.
// ---------------------------------------------------------------------------
__global__ void k0_prep(const float* __restrict__ w1, const float* __restrict__ w2,
                        unsigned short* __restrict__ w1f, unsigned short* __restrict__ w2f)
{
  const int i  = blockIdx.x * blockDim.x + threadIdx.x;   // 0..1023
  const int l  = i & 63;
  const int lr = l & 15, lq = l >> 4;
  if (i < 512) {
    const int frag = i >> 6;            // nt*4+kk
    const int nt = frag >> 2, kk = frag & 3;
    const int col = nt * 16 + lr;
    const int kb  = kk * 32 + lq * 8;
    bf16x8 v;
    #pragma unroll
    for (int j = 0; j < 8; ++j) v[j] = (short)f2bf(w1[(kb + j) * RDIM + col]);
    *(bf16x8*)&w1f[(size_t)i * 8] = v;
  } else {
    const int frag = (i - 512) >> 6;    // nt
    const int col = frag * 16 + lr;
    const int kb  = lq * 8;
    bf16x8 v;
    #pragma unroll
    for (int j = 0; j < 8; ++j) v[j] = (short)f2bf(w2[(kb + j) * DDIM + col]);
    *(bf16x8*)&w2f[(size_t)(i - 512) * 8] = v;
  }
}

// ---------------------------------------------------------------------------
// K1 (MFMA): x2 = x * (1 + tanh(relu(x@W1+b1)@W2+b2)) -> bf16 ws
// Block = 256 thr = 4 waves; 128 nodes/block; each wave owns 32 nodes.
// Frag layouts (16x16x32 bf16): A row=l&15, k=(l>>4)*8+j (contig);
//                               B col=l&15, k=(l>>4)*8+j;
//                               C/D col=l&15, row=(l>>4)*4+reg.
// ---------------------------------------------------------------------------
__global__ __launch_bounds__(BLK, 3) void k1_mfma(
    const float* __restrict__ x,
    const unsigned short* __restrict__ w1f, const float* __restrict__ b1,
    const unsigned short* __restrict__ w2f, const float* __restrict__ b2,
    unsigned short* __restrict__ x2, int N)
{
  __shared__ unsigned short xs[128 * 136];   // bf16 x tile, 272B row stride (34816 B)
  __shared__ unsigned short hs[128 * 40];    // bf16 h tile, 80B row stride (10240 B)

  const int t  = threadIdx.x;
  const int l  = t & 63;
  const int wv = t >> 6;
  const int wbase = wv * 32;               // this wave's node offset in tile
  const int base  = blockIdx.x * 128;
  const int cnt   = min(128, N - base);
  const int lr = l & 15;                   // tile row / col selector
  const int lq = l >> 4;                   // quad 0..3

  // ---- weight fragments: coalesced 16B/lane vector loads (L2-resident) ----
  bf16x8 w1r[2][4], w2r[8];
  #pragma unroll
  for (int nt = 0; nt < 2; ++nt)
    #pragma unroll
    for (int kk = 0; kk < 4; ++kk)
      w1r[nt][kk] = *(const bf16x8*)&w1f[(size_t)((nt * 4 + kk) * 64 + l) * 8];
  #pragma unroll
  for (int nt = 0; nt < 8; ++nt)
    w2r[nt] = *(const bf16x8*)&w2f[(size_t)(nt * 64 + l) * 8];

  float b1v[2], b2v[8];
  b1v[0] = b1[lr]; b1v[1] = b1[16 + lr];
  #pragma unroll
  for (int nt = 0; nt < 8; ++nt) b2v[nt] = b2[nt * 16 + lr];

  // ---- stage x tile: fp32 global -> bf16 LDS (coalesced float4) ----
  #pragma unroll
  for (int k = 0; k < 16; ++k) {
    int idx4 = t + k * BLK;                // 4096 float4 slots = 128 rows x 32
    int node = idx4 >> 5, c4 = idx4 & 31;
    float4 v = make_float4(0.f, 0.f, 0.f, 0.f);
    if (node < cnt) v = *(const float4*)&x[(size_t)(base + node) * DDIM + c4 * 4];
    ushort4 o;
    o.x = f2bf(v.x); o.y = f2bf(v.y); o.z = f2bf(v.z); o.w = f2bf(v.w);
    *(ushort4*)&xs[node * 136 + c4 * 4] = o;
  }
  __syncthreads();

  // ---- phase B: H = relu(X @ W1 + b1)  (2 Mtiles x 2 Ntiles x 4 Ksteps) ----
  f32x4 hacc[2][2];
  #pragma unroll
  for (int mt = 0; mt < 2; ++mt)
    #pragma unroll
    for (int nt = 0; nt < 2; ++nt)
      #pragma unroll
      for (int c = 0; c < 4; ++c) hacc[mt][nt][c] = b1v[nt];

  #pragma unroll
  for (int kk = 0; kk < 4; ++kk) {
    bf16x8 a0 = *(const bf16x8*)&xs[(wbase + lr)      * 136 + kk * 32 + lq * 8];
    bf16x8 a1 = *(const bf16x8*)&xs[(wbase + 16 + lr) * 136 + kk * 32 + lq * 8];
    hacc[0][0] = __builtin_amdgcn_mfma_f32_16x16x32_bf16(a0, w1r[0][kk], hacc[0][0], 0, 0, 0);
    hacc[0][1] = __builtin_amdgcn_mfma_f32_16x16x32_bf16(a0, w1r[1][kk], hacc[0][1], 0, 0, 0);
    hacc[1][0] = __builtin_amdgcn_mfma_f32_16x16x32_bf16(a1, w1r[0][kk], hacc[1][0], 0, 0, 0);
    hacc[1][1] = __builtin_amdgcn_mfma_f32_16x16x32_bf16(a1, w1r[1][kk], hacc[1][1], 0, 0, 0);
  }

  #pragma unroll
  for (int mt = 0; mt < 2; ++mt)
    #pragma unroll
    for (int nt = 0; nt < 2; ++nt)
      #pragma unroll
      for (int c = 0; c < 4; ++c) {
        int m = wbase + mt * 16 + lq * 4 + c;
        int r = nt * 16 + lr;
        hs[m * 40 + r] = f2bf(fmaxf(hacc[mt][nt][c], 0.f));
      }
  // (same-wave LDS RAW on hs; compiler inserts lgkmcnt)

  // ---- phase C: A2 = H @ W2 + b2  (2 Mtiles x 8 Ntiles x 1 Kstep) ----
  f32x4 cacc[2][8];
  #pragma unroll
  for (int mt = 0; mt < 2; ++mt)
    #pragma unroll
    for (int nt = 0; nt < 8; ++nt)
      #pragma unroll
      for (int c = 0; c < 4; ++c) cacc[mt][nt][c] = b2v[nt];

  bf16x8 ah0 = *(const bf16x8*)&hs[(wbase + lr)      * 40 + lq * 8];
  bf16x8 ah1 = *(const bf16x8*)&hs[(wbase + 16 + lr) * 40 + lq * 8];
  #pragma unroll
  for (int nt = 0; nt < 8; ++nt) {
    cacc[0][nt] = __builtin_amdgcn_mfma_f32_16x16x32_bf16(ah0, w2r[nt], cacc[0][nt], 0, 0, 0);
    cacc[1][nt] = __builtin_amdgcn_mfma_f32_16x16x32_bf16(ah1, w2r[nt], cacc[1][nt], 0, 0, 0);
  }

  // ---- epilogue: xs <- bf16( x * (1 + tanh(a)) ), in place ----
  #pragma unroll
  for (int mt = 0; mt < 2; ++mt)
    #pragma unroll
    for (int nt = 0; nt < 8; ++nt)
      #pragma unroll
      for (int c = 0; c < 4; ++c) {
        int m   = wbase + mt * 16 + lq * 4 + c;
        int col = nt * 16 + lr;
        int off = m * 136 + col;
        float a  = tanh_fast(cacc[mt][nt][c]);
        float xv = bf2f(xs[off]);
        xs[off]  = f2bf(xv * (1.f + a));
      }
  __syncthreads();

  // ---- coalesced bf16 store of x2 tile ----
  #pragma unroll
  for (int k = 0; k < 8; ++k) {
    int idx  = t + k * BLK;                // 2048 16B chunks = 128 rows x 16
    int node = idx >> 4, coff = (idx & 15) * 8;
    if (node < cnt)
      *(bf16x8*)&x2[(size_t)(base + node) * DDIM + coff] =
          *(const bf16x8*)&xs[node * 136 + coff];
  }
}

// ---------------------------------------------------------------------------
// K2: per-graph mean of x2 -> tg = tanh(mean @ W).  One block per graph.
// ---------------------------------------------------------------------------
__global__ void k2_mean_w(
    const unsigned short* __restrict__ x2, const int* __restrict__ batch,
    const float* __restrict__ W, float* __restrict__ tg, int N)
{
  __shared__ __align__(16) float part[8][132];
  __shared__ float meanv[DDIM];
  __shared__ int bounds[2];
  const int g = blockIdx.x, t = threadIdx.x;
  if (t == 0) bounds[0] = lower_bound(batch, N, g);
  if (t == 1) bounds[1] = lower_bound(batch, N, g + 1);
  __syncthreads();
  const int lo = bounds[0], hi = bounds[1];
  const int q = t & 31, s = t >> 5;

  float acc[4] = {0.f, 0.f, 0.f, 0.f};
  for (int n = lo + s; n < hi; n += 8) {
    ushort4 u = *(const ushort4*)&x2[(size_t)n * DDIM + q * 4];
    acc[0] += bf2f(u.x); acc[1] += bf2f(u.y); acc[2] += bf2f(u.z); acc[3] += bf2f(u.w);
  }
  *(float4*)&part[s][q * 4] = make_float4(acc[0], acc[1], acc[2], acc[3]);
  __syncthreads();

  if (t < DDIM) {
    float m = 0.f;
    #pragma unroll
    for (int s2 = 0; s2 < 8; ++s2) m += part[s2][t];
    float invc = (hi > lo) ? 1.f / (float)(hi - lo) : 0.f;
    meanv[t] = m * invc;
  }
  __syncthreads();

  if (t < DDIM) {
    float a = 0.f;
    #pragma unroll 8
    for (int k = 0; k < DDIM; ++k) a = fmaf(meanv[k], W[k * DDIM + t], a);
    tg[(size_t)g * DDIM + t] = tanh_fast(a);
  }
}

// ---------------------------------------------------------------------------
// K4: coefs = sigmoid(x2 . tg[g]); out[g] = sum coefs*x2.  One block per graph.
// ---------------------------------------------------------------------------
__global__ void k4_out(
    const unsigned short* __restrict__ x2, const int* __restrict__ batch,
    const float* __restrict__ tg, float* __restrict__ out, int N)
{
  __shared__ __align__(16) float part[8][132];
  __shared__ int bounds[2];
  const int g = blockIdx.x, t = threadIdx.x;
  if (t == 0) bounds[0] = lower_bound(batch, N, g);
  if (t == 1) bounds[1] = lower_bound(batch, N, g + 1);
  __syncthreads();
  const int lo = bounds[0], hi = bounds[1];
  const int q = t & 31, s = t >> 5;

  float4 tg4 = *(const float4*)&tg[(size_t)g * DDIM + q * 4];
  float tga[4] = {tg4.x, tg4.y, tg4.z, tg4.w};
  float acc[4] = {0.f, 0.f, 0.f, 0.f};

  for (int n = lo + s; n < hi; n += 8) {   // 32 lanes of a shuffle group share n
    ushort4 u = *(const ushort4*)&x2[(size_t)n * DDIM + q * 4];
    float xv[4] = {bf2f(u.x), bf2f(u.y), bf2f(u.z), bf2f(u.w)};
    float p = xv[0] * tga[0] + xv[1] * tga[1] + xv[2] * tga[2] + xv[3] * tga[3];
    #pragma unroll
    for (int off = 16; off >= 1; off >>= 1) p += __shfl_xor(p, off, 64);
    float coef = sigmoid_fast(p);
    #pragma unroll
    for (int c = 0; c < 4; ++c) acc[c] = fmaf(coef, xv[c], acc[c]);
  }
  *(float4*)&part[s][q * 4] = make_float4(acc[0], acc[1], acc[2], acc[3]);
  __syncthreads();

  if (t < DDIM) {
    float m = 0.f;
    #pragma unroll
    for (int s2 = 0; s2 < 8; ++s2) m += part[s2][t];
    out[(size_t)g * DDIM + t] = m;
  }
}

// ---------------------------------------------------------------------------
extern "C" void kernel_launch(void* const* d_in, const int* in_sizes, int n_in,
                              void* d_out, int out_size, void* d_ws, size_t ws_size,
                              hipStream_t stream) {
  const float* x     = (const float*)d_in[0];
  const int*   batch = (const int*)d_in[1];
  const float* w1 = (const float*)d_in[3];
  const float* b1 = (const float*)d_in[4];
  const float* w2 = (const float*)d_in[5];
  const float* b2 = (const float*)d_in[6];
  const float* W  = (const float*)d_in[7];
  float* out = (float*)d_out;

  const int N = in_sizes[0] / DDIM;
  const int G = out_size / DDIM;

  // ws layout: [tg: G*128 f32][w1f: 4096 bf16][w2f: 4096 bf16][x2: N*128 bf16]
  char* wsp = (char*)d_ws;
  float* tg = (float*)wsp;
  unsigned short* w1f = (unsigned short*)(wsp + (size_t)G * DDIM * sizeof(float));
  unsigned short* w2f = w1f + 4096;
  unsigned short* x2  = w2f + 4096;
  (void)ws_size; (void)n_in;

  hipLaunchKernelGGL(k0_prep, dim3(4), dim3(BLK), 0, stream, w1, w2, w1f, w2f);
  const int grid1 = (N + 127) / 128;
  hipLaunchKernelGGL(k1_mfma, dim3(grid1), dim3(BLK), 0, stream, x, w1f, b1, w2f, b2, x2, N);
  hipLaunchKernelGGL(k2_mean_w, dim3(G), dim3(BLK), 0, stream, x2, batch, W, tg, N);
  hipLaunchKernelGGL(k4_out, dim3(G), dim3(BLK), 0, stream, x2, batch, tg, out, N);
}

// Round 4
// 154.151 us; speedup vs baseline: 1.1535x; 1.1535x over previous
//
#include <hip/hip_runtime.h>

#define DDIM 128
#define RDIM 32
#define BLK  256
#define XSTR 136   // xs row stride (u16); 272B = 16B-aligned rows
#define HSTR 40    // hs row stride (u16); 80B

typedef __attribute__((ext_vector_type(8))) short bf16x8;
typedef __attribute__((ext_vector_type(4))) float f32x4;

__device__ __forceinline__ float tanh_fast(float v) {
  float e = __expf(2.f * v);
  return 1.f - 2.f / (e + 1.f);
}
__device__ __forceinline__ float sigmoid_fast(float v) {
  return 1.f / (1.f + __expf(-v));
}
__device__ __forceinline__ unsigned short f2bf(float f) {  // RNE f32->bf16
  unsigned u = __float_as_uint(f);
  u += 0x7fffu + ((u >> 16) & 1u);
  return (unsigned short)(u >> 16);
}
__device__ __forceinline__ float bf2f(unsigned short s) {
  return __uint_as_float(((unsigned)s) << 16);
}
__device__ __forceinline__ int lower_bound(const int* __restrict__ b, int n, int v) {
  int lo = 0, hi = n;
  while (lo < hi) { int m = (lo + hi) >> 1; if (b[m] < v) lo = m + 1; else hi = m; }
  return lo;
}

// ---------------------------------------------------------------------------
// K0: one-time build of bf16 MFMA weight fragments in ws.
//   w1f: [frag=nt*4+kk][lane][8]  (512 x 8 bf16)
//   w2f: [nt][lane][8]            (512 x 8 bf16)
// B-frag layout (16x16x32): col=l&15, k=(l>>4)*8+j.
// ---------------------------------------------------------------------------
__global__ void k0_prep(const float* __restrict__ w1, const float* __restrict__ w2,
                        unsigned short* __restrict__ w1f, unsigned short* __restrict__ w2f)
{
  const int i  = blockIdx.x * blockDim.x + threadIdx.x;   // 0..1023
  const int l  = i & 63;
  const int lr = l & 15, lq = l >> 4;
  if (i < 512) {
    const int frag = i >> 6;            // nt*4+kk
    const int nt = frag >> 2, kk = frag & 3;
    const int col = nt * 16 + lr;
    const int kb  = kk * 32 + lq * 8;
    bf16x8 v;
    #pragma unroll
    for (int j = 0; j < 8; ++j) v[j] = (short)f2bf(w1[(kb + j) * RDIM + col]);
    *(bf16x8*)&w1f[(size_t)i * 8] = v;
  } else {
    const int frag = (i - 512) >> 6;    // nt
    const int col = frag * 16 + lr;
    const int kb  = lq * 8;
    bf16x8 v;
    #pragma unroll
    for (int j = 0; j < 8; ++j) v[j] = (short)f2bf(w2[(kb + j) * DDIM + col]);
    *(bf16x8*)&w2f[(size_t)(i - 512) * 8] = v;
  }
}

// ---------------------------------------------------------------------------
// K1 (wave-autonomous MFMA): x2 = x*(1+tanh(relu(x@W1+b1)@W2+b2)) -> bf16 ws
// 4 waves/block, each wave owns 16 nodes + private LDS; NO __syncthreads.
// Frag layouts (16x16x32 bf16): A row=l&15, k=(l>>4)*8+j;
//                               B col=l&15, k=(l>>4)*8+j;
//                               C/D col=l&15, row=(l>>4)*4+reg.
// ---------------------------------------------------------------------------
__global__ __launch_bounds__(BLK, 3) void k1_mfma(
    const float* __restrict__ x,
    const unsigned short* __restrict__ w1f, const float* __restrict__ b1,
    const unsigned short* __restrict__ w2f, const float* __restrict__ b2,
    unsigned short* __restrict__ x2, int N)
{
  __shared__ unsigned short xs4[4][16 * XSTR];   // 4 x 4352 B
  __shared__ unsigned short hs4[4][16 * HSTR];   // 4 x 1280 B

  const int t  = threadIdx.x;
  const int l  = t & 63;
  const int wv = t >> 6;
  const int lr = l & 15;
  const int lq = l >> 4;
  const int node0 = (blockIdx.x * 4 + wv) * 16;
  if (node0 >= N) return;
  unsigned short* xs = xs4[wv];
  unsigned short* hs = hs4[wv];

  // ---- weight fragments: coalesced 16B/lane loads (L2-resident) ----
  bf16x8 w1r[2][4], w2r[8];
  #pragma unroll
  for (int nt = 0; nt < 2; ++nt)
    #pragma unroll
    for (int kk = 0; kk < 4; ++kk)
      w1r[nt][kk] = *(const bf16x8*)&w1f[(size_t)((nt * 4 + kk) * 64 + l) * 8];
  #pragma unroll
  for (int nt = 0; nt < 8; ++nt)
    w2r[nt] = *(const bf16x8*)&w2f[(size_t)(nt * 64 + l) * 8];

  float b1v[2], b2v[8];
  b1v[0] = b1[lr]; b1v[1] = b1[16 + lr];
  #pragma unroll
  for (int nt = 0; nt < 8; ++nt) b2v[nt] = b2[nt * 16 + lr];

  // ---- stage 16 nodes x 128 f32 -> bf16 LDS (coalesced float4) ----
  #pragma unroll
  for (int j = 0; j < 8; ++j) {
    int i = l + j * 64;                  // 512 float4 slots = 16 rows x 32
    int node = i >> 5, c4 = (i & 31) << 2;
    float4 v = make_float4(0.f, 0.f, 0.f, 0.f);
    if (node0 + node < N) v = *(const float4*)&x[(size_t)(node0 + node) * DDIM + c4];
    ushort4 o;
    o.x = f2bf(v.x); o.y = f2bf(v.y); o.z = f2bf(v.z); o.w = f2bf(v.w);
    *(ushort4*)&xs[node * XSTR + c4] = o;
  }
  // same-wave LDS consumption below; compiler inserts lgkmcnt (no barrier)

  // ---- phase B: H = relu(X @ W1 + b1)  (2 Ntiles x 4 Ksteps) ----
  f32x4 hacc[2];
  #pragma unroll
  for (int nt = 0; nt < 2; ++nt)
    #pragma unroll
    for (int c = 0; c < 4; ++c) hacc[nt][c] = b1v[nt];

  #pragma unroll
  for (int kk = 0; kk < 4; ++kk) {
    bf16x8 a = *(const bf16x8*)&xs[lr * XSTR + kk * 32 + lq * 8];
    hacc[0] = __builtin_amdgcn_mfma_f32_16x16x32_bf16(a, w1r[0][kk], hacc[0], 0, 0, 0);
    hacc[1] = __builtin_amdgcn_mfma_f32_16x16x32_bf16(a, w1r[1][kk], hacc[1], 0, 0, 0);
  }

  #pragma unroll
  for (int nt = 0; nt < 2; ++nt)
    #pragma unroll
    for (int c = 0; c < 4; ++c)
      hs[(lq * 4 + c) * HSTR + nt * 16 + lr] = f2bf(fmaxf(hacc[nt][c], 0.f));

  // ---- phase C: A2 = H @ W2 + b2  (8 Ntiles, K=32) ----
  bf16x8 ah = *(const bf16x8*)&hs[lr * HSTR + lq * 8];
  f32x4 cacc[8];
  #pragma unroll
  for (int nt = 0; nt < 8; ++nt)
    #pragma unroll
    for (int c = 0; c < 4; ++c) cacc[nt][c] = b2v[nt];
  #pragma unroll
  for (int nt = 0; nt < 8; ++nt)
    cacc[nt] = __builtin_amdgcn_mfma_f32_16x16x32_bf16(ah, w2r[nt], cacc[nt], 0, 0, 0);

  // ---- gate in LDS: xs <- bf16( x * (1 + tanh(a)) ) ----
  #pragma unroll
  for (int nt = 0; nt < 8; ++nt)
    #pragma unroll
    for (int c = 0; c < 4; ++c) {
      int m   = lq * 4 + c;
      int col = nt * 16 + lr;
      int off = m * XSTR + col;
      float a  = tanh_fast(cacc[nt][c]);
      float xv = bf2f(xs[off]);
      xs[off]  = f2bf(xv * (1.f + a));
    }

  // ---- coalesced bf16 store ----
  #pragma unroll
  for (int k = 0; k < 4; ++k) {
    int idx  = l + k * 64;               // 256 chunks = 16 rows x 16
    int node = idx >> 4, coff = (idx & 15) * 8;
    if (node0 + node < N)
      *(bf16x8*)&x2[(size_t)(node0 + node) * DDIM + coff] =
          *(const bf16x8*)&xs[node * XSTR + coff];
  }
}

// ---------------------------------------------------------------------------
// K3 (fused k2+k4): per-graph mean -> tg=tanh(mean@W) in LDS -> coef pass.
// One block per graph; x2 rows hit L2 on the second pass.
// ---------------------------------------------------------------------------
__global__ void k3_graph(
    const unsigned short* __restrict__ x2, const int* __restrict__ batch,
    const float* __restrict__ W, float* __restrict__ out, int N)
{
  __shared__ __align__(16) float part[8][132];
  __shared__ float meanv[DDIM];
  __shared__ float tgs[DDIM];
  __shared__ int bounds[2];
  const int g = blockIdx.x, t = threadIdx.x;
  if (t == 0) bounds[0] = lower_bound(batch, N, g);
  if (t == 1) bounds[1] = lower_bound(batch, N, g + 1);
  __syncthreads();
  const int lo = bounds[0], hi = bounds[1];
  const int q = t & 31, s = t >> 5;

  // ---- phase 1: segment mean ----
  {
    float acc[4] = {0.f, 0.f, 0.f, 0.f};
    for (int n = lo + s; n < hi; n += 8) {
      ushort4 u = *(const ushort4*)&x2[(size_t)n * DDIM + q * 4];
      acc[0] += bf2f(u.x); acc[1] += bf2f(u.y); acc[2] += bf2f(u.z); acc[3] += bf2f(u.w);
    }
    *(float4*)&part[s][q * 4] = make_float4(acc[0], acc[1], acc[2], acc[3]);
  }
  __syncthreads();
  if (t < DDIM) {
    float m = 0.f;
    #pragma unroll
    for (int s2 = 0; s2 < 8; ++s2) m += part[s2][t];
    float invc = (hi > lo) ? 1.f / (float)(hi - lo) : 0.f;
    meanv[t] = m * invc;
  }
  __syncthreads();

  // ---- phase 2: tg = tanh(mean @ W) ----
  if (t < DDIM) {
    float a = 0.f;
    #pragma unroll 8
    for (int k = 0; k < DDIM; ++k) a = fmaf(meanv[k], W[k * DDIM + t], a);
    tgs[t] = tanh_fast(a);
  }
  __syncthreads();

  // ---- phase 3: coefs = sigmoid(x2 . tg); out = sum coefs*x2 ----
  float4 tg4 = *(const float4*)&tgs[q * 4];
  float tga[4] = {tg4.x, tg4.y, tg4.z, tg4.w};
  float acc[4] = {0.f, 0.f, 0.f, 0.f};
  for (int n = lo + s; n < hi; n += 8) {   // 32 lanes of a shuffle group share n
    ushort4 u = *(const ushort4*)&x2[(size_t)n * DDIM + q * 4];
    float xv[4] = {bf2f(u.x), bf2f(u.y), bf2f(u.z), bf2f(u.w)};
    float p = xv[0] * tga[0] + xv[1] * tga[1] + xv[2] * tga[2] + xv[3] * tga[3];
    #pragma unroll
    for (int off = 16; off >= 1; off >>= 1) p += __shfl_xor(p, off, 64);
    float coef = sigmoid_fast(p);
    #pragma unroll
    for (int c = 0; c < 4; ++c) acc[c] = fmaf(coef, xv[c], acc[c]);
  }
  *(float4*)&part[s][q * 4] = make_float4(acc[0], acc[1], acc[2], acc[3]);
  __syncthreads();

  if (t < DDIM) {
    float m = 0.f;
    #pragma unroll
    for (int s2 = 0; s2 < 8; ++s2) m += part[s2][t];
    out[(size_t)g * DDIM + t] = m;
  }
}

// ---------------------------------------------------------------------------
extern "C" void kernel_launch(void* const* d_in, const int* in_sizes, int n_in,
                              void* d_out, int out_size, void* d_ws, size_t ws_size,
                              hipStream_t stream) {
  const float* x     = (const float*)d_in[0];
  const int*   batch = (const int*)d_in[1];
  const float* w1 = (const float*)d_in[3];
  const float* b1 = (const float*)d_in[4];
  const float* w2 = (const float*)d_in[5];
  const float* b2 = (const float*)d_in[6];
  const float* W  = (const float*)d_in[7];
  float* out = (float*)d_out;

  const int N = in_sizes[0] / DDIM;
  const int G = out_size / DDIM;

  // ws layout: [w1f: 4096 bf16][w2f: 4096 bf16][x2: N*128 bf16]
  unsigned short* w1f = (unsigned short*)d_ws;
  unsigned short* w2f = w1f + 4096;
  unsigned short* x2  = w2f + 4096;
  (void)ws_size; (void)n_in;

  hipLaunchKernelGGL(k0_prep, dim3(4), dim3(BLK), 0, stream, w1, w2, w1f, w2f);
  const int grid1 = (N + 63) / 64;          // 64 nodes per block (4 waves x 16)
  hipLaunchKernelGGL(k1_mfma, dim3(grid1), dim3(BLK), 0, stream, x, w1f, b1, w2f, b2, x2, N);
  hipLaunchKernelGGL(k3_graph, dim3(G), dim3(BLK), 0, stream, x2, batch, W, out, N);
}